// Round 1
// baseline (150.943 us; speedup 1.0000x reference)
//
#include <hip/hip_runtime.h>

// Problem shape (fixed by setup_inputs): B=4, L=4096, D=1024 (D derived at launch).
#define BB   4
#define LL   4096
#define KCH  64                       // boundaries per chunk
#define CMAX ((LL + KCH - 1) / KCH)   // 64 max chunks per batch
#define EPSP 1e-4f

// ---------------- kernel 1: boundary extraction (stable order) ----------------
// grid = B, block = 256. Each thread owns LL/256 = 16 contiguous positions.
__global__ void k_setup(const float* __restrict__ bp, const int* __restrict__ mask,
                        int* __restrict__ nb, int* __restrict__ bpos,
                        float* __restrict__ pk) {
    const int b   = blockIdx.x;
    const int tid = threadIdx.x;
    const int PER = LL / 256;
    const int base = tid * PER;

    int cnt = 0;
    for (int i = 0; i < PER; ++i) cnt += (mask[b * LL + base + i] != 0);

    __shared__ int s[256];
    s[tid] = cnt;
    __syncthreads();
    // Hillis-Steele inclusive scan over thread sums
    for (int off = 1; off < 256; off <<= 1) {
        int v = (tid >= off) ? s[tid - off] : 0;
        __syncthreads();
        s[tid] += v;
        __syncthreads();
    }
    int k = s[tid] - cnt;      // exclusive prefix = first boundary index for this thread
    const int total = s[255];

    for (int i = 0; i < PER; ++i) {
        int t = base + i;
        if (mask[b * LL + t] != 0) {
            bpos[b * (LL + 1) + k] = t;
            float p = bp[(size_t)(b * LL + t) * 2 + 1];
            p = fminf(fmaxf(p, EPSP), 1.0f - EPSP);
            pk[b * LL + k] = p;
            ++k;
        }
    }
    if (tid == 0) {
        nb[b] = total;
        bpos[b * (LL + 1) + total] = LL;   // sentinel: last segment ends at L
    }
}

// ---------------- kernel 2: per-chunk local scan -> U[b,c,d], A[b,c] ----------------
// grid = (CMAX, B, D/256), block = 256 (one d per thread)
__global__ void k_chunk(const float* __restrict__ X, const int* __restrict__ nb,
                        const float* __restrict__ pk, float* __restrict__ U,
                        float* __restrict__ Adec, int D) {
    const int c = blockIdx.x, b = blockIdx.y;
    const int d = blockIdx.z * blockDim.x + threadIdx.x;
    const int n  = nb[b];
    const int k0 = c * KCH;
    if (k0 >= n) return;
    const int k1 = (k0 + KCH < n) ? (k0 + KCH) : n;
    const int nk = k1 - k0;

    __shared__ float sp[KCH];
    if ((int)threadIdx.x < nk) sp[threadIdx.x] = pk[b * LL + k0 + threadIdx.x];
    __syncthreads();

    float h = 0.0f, A = 1.0f;
    const float* xp = X + ((size_t)(b * LL + k0)) * D + d;
    for (int k = 0; k < nk; ++k) {
        float p = sp[k];
        float x = xp[(size_t)k * D];
        h = fmaf(p, x - h, h);     // (1-p)*h + p*x
        A *= (1.0f - p);
    }
    U[((size_t)(b * CMAX + c)) * D + d] = h;
    if (threadIdx.x == 0 && blockIdx.z == 0) Adec[b * CMAX + c] = A;
}

// ---------------- kernel 3: cross-chunk fixup + local scan + segment broadcast ----------------
// grid = (CMAX, B, D/256), block = 256
__global__ void k_scan_out(const float* __restrict__ X, const int* __restrict__ nb,
                           const float* __restrict__ pk, const int* __restrict__ bpos,
                           const float* __restrict__ U, const float* __restrict__ Adec,
                           float* __restrict__ out, int D) {
    const int c = blockIdx.x, b = blockIdx.y;
    const int d = blockIdx.z * blockDim.x + threadIdx.x;
    const int n  = nb[b];
    const int k0 = c * KCH;
    if (k0 >= n) return;
    const int k1 = (k0 + KCH < n) ? (k0 + KCH) : n;
    const int nk = k1 - k0;

    __shared__ float sp[KCH];
    __shared__ int   sb[KCH + 1];
    if ((int)threadIdx.x < nk)     sp[threadIdx.x] = pk[b * LL + k0 + threadIdx.x];
    if ((int)threadIdx.x < nk + 1) sb[threadIdx.x] = bpos[b * (LL + 1) + k0 + threadIdx.x];
    __syncthreads();

    // incoming state from all previous (full) chunks: short recurrence, L2-resident
    float H = 0.0f;
    for (int cc = 0; cc < c; ++cc) {
        float A = Adec[b * CMAX + cc];
        float u = U[((size_t)(b * CMAX + cc)) * D + d];
        H = fmaf(A, H, u);
    }

    float h = H;
    const float* xp = X + ((size_t)(b * LL + k0)) * D + d;
    float* op = out + (size_t)b * LL * D + d;
    for (int k = 0; k < nk; ++k) {
        float p = sp[k];
        float x = xp[(size_t)k * D];
        h = fmaf(p, x - h, h);
        int t0 = sb[k], t1 = sb[k + 1];
        for (int t = t0; t < t1; ++t) op[(size_t)t * D] = h;   // coalesced across d
    }
}

extern "C" void kernel_launch(void* const* d_in, const int* in_sizes, int n_in,
                              void* d_out, int out_size, void* d_ws, size_t ws_size,
                              hipStream_t stream) {
    const float* X    = (const float*)d_in[0];   // hidden_states (B,L,D) f32
    const float* bp   = (const float*)d_in[1];   // boundary_prob (B,L,2) f32
    const int*   mask = (const int*)d_in[2];     // boundary_mask (B,L)   int32 (bool)
    float*       out  = (float*)d_out;           // (B,L,D) f32

    const int D = in_sizes[0] / in_sizes[2];     // 1024

    // workspace carve (all 4-byte types, ~1.2 MiB total)
    char* w = (char*)d_ws;
    int*   nb   = (int*)w;   w += 256;
    int*   bpos = (int*)w;   w += sizeof(int)   * BB * (LL + 1);
    float* pk   = (float*)w; w += sizeof(float) * BB * LL;
    float* Adec = (float*)w; w += sizeof(float) * BB * CMAX;
    float* U    = (float*)w; // BB*CMAX*D floats

    k_setup<<<BB, 256, 0, stream>>>(bp, mask, nb, bpos, pk);

    dim3 grid(CMAX, BB, D / 256);
    k_chunk<<<grid, 256, 0, stream>>>(X, nb, pk, U, Adec, D);
    k_scan_out<<<grid, 256, 0, stream>>>(X, nb, pk, bpos, U, Adec, out, D);
}

// Round 2
// 136.956 us; speedup vs baseline: 1.1021x; 1.1021x over previous
//
#include <hip/hip_runtime.h>

// Shape fixed by setup_inputs: B=4, L=4096, D=1024 (D re-derived at launch).
#define BB   4
#define LL   4096
#define KCH  16                  // boundaries per chunk
#define CMAX (LL / KCH)          // 256 worst-case chunks (all tokens boundaries)
#define EPSP 1e-4f

// ---------------- kernel 1: boundary extraction (stable order) ----------------
// grid = B, block = 256. Each thread owns LL/256 = 16 contiguous positions.
__global__ void k_setup(const float* __restrict__ bp, const int* __restrict__ mask,
                        int* __restrict__ nb, int* __restrict__ bpos,
                        float* __restrict__ pk) {
    const int b   = blockIdx.x;
    const int tid = threadIdx.x;
    const int PER = LL / 256;
    const int base = tid * PER;

    int m[PER];
    int cnt = 0;
    for (int i = 0; i < PER; ++i) { m[i] = mask[b * LL + base + i]; cnt += (m[i] != 0); }

    __shared__ int s[256];
    s[tid] = cnt;
    __syncthreads();
    for (int off = 1; off < 256; off <<= 1) {      // Hillis-Steele inclusive scan
        int v = (tid >= off) ? s[tid - off] : 0;
        __syncthreads();
        s[tid] += v;
        __syncthreads();
    }
    int k = s[tid] - cnt;                          // exclusive prefix
    const int total = s[255];

    for (int i = 0; i < PER; ++i) {
        if (m[i] != 0) {
            int t = base + i;
            bpos[b * (LL + 1) + k] = t;
            float p = bp[(size_t)(b * LL + t) * 2 + 1];
            p = fminf(fmaxf(p, EPSP), 1.0f - EPSP);
            pk[b * LL + k] = p;
            ++k;
        }
    }
    if (tid == 0) {
        nb[b] = total;
        bpos[b * (LL + 1) + total] = LL;           // sentinel
    }
}

__device__ __forceinline__ void ema4(float4& h, float p, const float4 x) {
    h.x = fmaf(p, x.x - h.x, h.x);
    h.y = fmaf(p, x.y - h.y, h.y);
    h.z = fmaf(p, x.z - h.z, h.z);
    h.w = fmaf(p, x.w - h.w, h.w);
}

// ---------------- kernel 2: per-chunk local scan -> U[b,c,:], Adec[b,c] --------
// grid = (CMAX, B), block = 256, one float4 (4 channels) per thread.
__global__ __launch_bounds__(256) void
k_chunk(const float4* __restrict__ X4, const int* __restrict__ nb,
        const float* __restrict__ pk, float4* __restrict__ U4,
        float* __restrict__ Adec, int D4) {
    const int c = blockIdx.x, b = blockIdx.y;
    const int n  = nb[b];
    const int k0 = c * KCH;
    if (k0 >= n) return;
    const int nk = (k0 + KCH < n) ? KCH : (n - k0);
    const int tid = threadIdx.x;

    __shared__ float sp[KCH];
    if (tid < nk) sp[tid] = pk[b * LL + k0 + tid];
    __syncthreads();

    const float4* xp = X4 + (size_t)(b * LL + k0) * D4 + tid;
    float4 h = {0.f, 0.f, 0.f, 0.f};
    float  A = 1.0f;
    if (nk == KCH) {
#pragma unroll
        for (int k = 0; k < KCH; ++k) {
            float p = sp[k];
            ema4(h, p, xp[(size_t)k * D4]);
            A *= (1.0f - p);
        }
    } else {
        for (int k = 0; k < nk; ++k) {
            float p = sp[k];
            ema4(h, p, xp[(size_t)k * D4]);
            A *= (1.0f - p);
        }
    }
    U4[(size_t)(b * CMAX + c) * D4 + tid] = h;
    if (tid == 0) Adec[b * CMAX + c] = A;
}

// ---------------- kernel 3: cross-chunk fixup + local scan + segment stores ----
// grid = (CMAX, B), block = 256, float4 per thread. Fully vectorized stores.
__global__ __launch_bounds__(256) void
k_scan_out(const float4* __restrict__ X4, const int* __restrict__ nb,
           const float* __restrict__ pk, const int* __restrict__ bpos,
           const float4* __restrict__ U4, const float* __restrict__ Adec,
           float4* __restrict__ out4, int D4) {
    const int c = blockIdx.x, b = blockIdx.y;
    const int n  = nb[b];
    const int k0 = c * KCH;
    if (k0 >= n) return;
    const int nk = (k0 + KCH < n) ? KCH : (n - k0);
    const int tid = threadIdx.x;

    __shared__ float sp[KCH];
    __shared__ int   sb[KCH + 1];
    __shared__ float sA[CMAX];
    if (tid < nk)     sp[tid] = pk[b * LL + k0 + tid];
    if (tid < nk + 1) sb[tid] = bpos[b * (LL + 1) + k0 + tid];
    if (tid < c)      sA[tid] = Adec[b * CMAX + tid];
    __syncthreads();

    // incoming state: recurrence over previous chunks' (A, U); U rows L2-resident
    float4 H = {0.f, 0.f, 0.f, 0.f};
    const float4* up = U4 + (size_t)b * CMAX * D4 + tid;
    for (int cc = 0; cc < c; ++cc) {
        float A = sA[cc];
        float4 u = up[(size_t)cc * D4];
        H.x = fmaf(A, H.x, u.x);
        H.y = fmaf(A, H.y, u.y);
        H.z = fmaf(A, H.z, u.z);
        H.w = fmaf(A, H.w, u.w);
    }

    const float4* xp = X4 + (size_t)(b * LL + k0) * D4 + tid;
    float4*       op = out4 + (size_t)b * LL * D4 + tid;
    float4 h = H;
    for (int k = 0; k < nk; ++k) {
        float p = sp[k];
        ema4(h, p, xp[(size_t)k * D4]);
        const int t0 = sb[k], t1 = sb[k + 1];
        for (int t = t0; t < t1; ++t)
            op[(size_t)t * D4] = h;              // 16 B/lane, coalesced across block
    }
}

extern "C" void kernel_launch(void* const* d_in, const int* in_sizes, int n_in,
                              void* d_out, int out_size, void* d_ws, size_t ws_size,
                              hipStream_t stream) {
    const float* X    = (const float*)d_in[0];   // hidden_states (B,L,D) f32
    const float* bp   = (const float*)d_in[1];   // boundary_prob (B,L,2) f32
    const int*   mask = (const int*)d_in[2];     // boundary_mask (B,L)
    float*       out  = (float*)d_out;           // (B,L,D) f32

    const int D  = in_sizes[0] / in_sizes[2];    // 1024
    const int D4 = D / 4;

    // workspace carve (offsets kept 16B-aligned; total < 4.2 MiB)
    char* w = (char*)d_ws;
    int*   nb   = (int*)w;   w += 256;
    int*   bpos = (int*)w;   w += sizeof(int)   * BB * (LL + 1);   // 65552
    float* pk   = (float*)w; w += sizeof(float) * BB * LL;         // 65536
    float* Adec = (float*)w; w += sizeof(float) * BB * CMAX;       // 4096
    float* U    = (float*)w;                                       // BB*CMAX*D floats

    k_setup<<<BB, 256, 0, stream>>>(bp, mask, nb, bpos, pk);

    dim3 grid(CMAX, BB);
    k_chunk<<<grid, 256, 0, stream>>>((const float4*)X, nb, pk,
                                      (float4*)U, Adec, D4);
    k_scan_out<<<grid, 256, 0, stream>>>((const float4*)X, nb, pk, bpos,
                                         (const float4*)U, Adec,
                                         (float4*)out, D4);
}